// Round 11
// baseline (527.413 us; speedup 1.0000x reference)
//
#include <hip/hip_runtime.h>
#include <stdint.h>

typedef short s16x8 __attribute__((ext_vector_type(8)));
typedef float f32x4 __attribute__((ext_vector_type(4)));

__device__ __forceinline__ unsigned short f2bf(float f) {
  union { float f; unsigned int u; } v; v.f = f;
  unsigned int r = v.u + 0x7FFFu + ((v.u >> 16) & 1u);
  return (unsigned short)(r >> 16);
}

// HW packed f32x2 -> e4m3x2 (low word: byte0=cvt(a), byte1=cvt(b))
__device__ __forceinline__ unsigned cvt2fp8(float a, float b) {
#if __has_builtin(__builtin_amdgcn_cvt_pk_fp8_f32)
  return (unsigned)__builtin_amdgcn_cvt_pk_fp8_f32(a, b, 0, false);
#else
  unsigned r;
  asm("v_cvt_pk_fp8_f32 %0, %1, %2" : "=v"(r) : "v"(a), "v"(b));
  return r;
#endif
}

__device__ __forceinline__ void gload_lds16(const void* g, void* l) {
  __builtin_amdgcn_global_load_lds(
      (const __attribute__((address_space(1))) unsigned int*)g,
      (__attribute__((address_space(3))) unsigned int*)l, 16, 0, 0);
}

// T1 XCD-aware bijective block swizzle (grid size must be %8==0; all ours are).
__device__ __forceinline__ unsigned xcd_swz(unsigned fid, unsigned nwg) {
  unsigned cpx = nwg >> 3;
  return (fid & 7) * cpx + (fid >> 3);
}

// ---------------- converts ----------------
__global__ void conv_bf16(const float* __restrict__ in, unsigned short* __restrict__ out, int n8) {
  int i = blockIdx.x * blockDim.x + threadIdx.x;
  if (i >= n8) return;
  const f32x4* p = (const f32x4*)(in + (long)i * 8);
  f32x4 a = p[0], b = p[1];
  s16x8 o;
  o[0]=(short)f2bf(a[0]); o[1]=(short)f2bf(a[1]); o[2]=(short)f2bf(a[2]); o[3]=(short)f2bf(a[3]);
  o[4]=(short)f2bf(b[0]); o[5]=(short)f2bf(b[1]); o[6]=(short)f2bf(b[2]); o[7]=(short)f2bf(b[3]);
  *(s16x8*)(out + (long)i * 8) = o;
}

// X f32 -> bf16 AND fp8 e4m3 in one pass (read X once)
__global__ void conv_x(const float* __restrict__ in, unsigned short* __restrict__ obf,
                       unsigned char* __restrict__ of8, int n8) {
  int i = blockIdx.x * blockDim.x + threadIdx.x;
  if (i >= n8) return;
  const f32x4* p = (const f32x4*)(in + (long)i * 8);
  f32x4 a = p[0], b = p[1];
  s16x8 o;
  o[0]=(short)f2bf(a[0]); o[1]=(short)f2bf(a[1]); o[2]=(short)f2bf(a[2]); o[3]=(short)f2bf(a[3]);
  o[4]=(short)f2bf(b[0]); o[5]=(short)f2bf(b[1]); o[6]=(short)f2bf(b[2]); o[7]=(short)f2bf(b[3]);
  *(s16x8*)(obf + (long)i * 8) = o;
  unsigned long w = (unsigned long)(cvt2fp8(a[0], a[1]) & 0xFFFFu)
                  | ((unsigned long)(cvt2fp8(a[2], a[3]) & 0xFFFFu) << 16)
                  | ((unsigned long)(cvt2fp8(b[0], b[1]) & 0xFFFFu) << 32)
                  | ((unsigned long)(cvt2fp8(b[2], b[3]) & 0xFFFFu) << 48);
  *(unsigned long*)(of8 + (long)i * 8) = w;
}

// Wv: [16][1024][64] f32 -> WvT [16][64][1024] bf16
__global__ void convT_wv(const float* __restrict__ in, unsigned short* __restrict__ out) {
  int i = blockIdx.x * blockDim.x + threadIdx.x; // 1M
  int v = i & 63, d = (i >> 6) & 1023, h = i >> 16;
  out[((long)h * 64 + v) * 1024 + d] = f2bf(in[i]);
}

// Wo: [1024][1024] f32 [c][e] -> WoT [e][c] bf16
__global__ void convT_wo(const float* __restrict__ in, unsigned short* __restrict__ out) {
  int i = blockIdx.x * blockDim.x + threadIdx.x; // 1M
  int e = i & 1023, c = i >> 10;
  out[(long)e * 1024 + c] = f2bf(in[i]);
}

// ---------------- generic bt-GEMM, K=1024 fixed ----------------
// C[i][j] = sum_k A[i][k] * BT[j][k];  A,BT bf16 row-major with ld=1024.
// CMODE 0: bf16 C[row*ldc+col]; 1: bf16 transposed C[col*ldc+row];
// 2: f32 masked (col>row -> -1e9); 3: fp8 e4m3 of (v/256) via HW cvt.
template<int BM, int BN, int WAVES_M, int WAVES_N, int CMODE>
__global__ __launch_bounds__(256, 2)
void gemm_bt(const unsigned short* __restrict__ A, const unsigned short* __restrict__ BT,
             void* __restrict__ Cout, int aDiv, long aStr, int bMod, long bStr,
             long cStr, int ldc)
{
  constexpr int BK = 64;
  constexpr int FM = BM / (WAVES_M * 16);
  constexpr int FN = BN / (WAVES_N * 16);
  __shared__ __align__(16) unsigned short At[BM * BK];
  __shared__ __align__(16) unsigned short Bt[BN * BK];

  // T1 XCD swizzle
  unsigned fid = blockIdx.x + gridDim.x * (blockIdx.y + gridDim.y * blockIdx.z);
  unsigned nwg = gridDim.x * gridDim.y * gridDim.z;
  unsigned sid = xcd_swz(fid, nwg);
  unsigned bx = sid % gridDim.x;
  unsigned rem = sid / gridDim.x;
  unsigned by = rem % gridDim.y;
  unsigned bz = rem / gridDim.y;

  const int t = threadIdx.x;
  const int l = t & 63;
  const int g = l >> 4, c = l & 15;
  const int w = t >> 6;
  const int wr = (w / WAVES_N) * (BM / WAVES_M);
  const int wc = (w % WAVES_N) * (BN / WAVES_N);
  const int z = bz;
  const int m0 = by * BM;
  const int n0 = bx * BN;
  const unsigned short* Ab = A + (long)(z / aDiv) * aStr + (long)m0 * 1024;
  const unsigned short* Bb = BT + (long)(z % bMod) * bStr + (long)n0 * 1024;

  const long cbase = (long)z * cStr;

  // fully-masked output tile (col > row everywhere): skip the GEMM entirely
  if constexpr (CMODE == 2) {
    if (n0 > m0 + BM - 1) {
#pragma unroll
      for (int m = 0; m < FM; ++m)
#pragma unroll
        for (int n = 0; n < FN; ++n)
#pragma unroll
          for (int r = 0; r < 4; ++r) {
            int row = wr + m * 16 + g * 4 + r;
            int col = n0 + wc + n * 16 + c;
            ((float*)Cout)[cbase + (long)(m0 + row) * ldc + col] = -1e9f;
          }
      return;
    }
  }

  f32x4 acc[FM][FN] = {};
  constexpr int PA = (BM * BK) / 2048;
  constexpr int PB = (BN * BK) / 2048;

  for (int k0 = 0; k0 < 1024; k0 += BK) {
#pragma unroll
    for (int p = 0; p < PA; ++p) {
      int e = (p * 256 + t) * 8;
      int row = e >> 6, col = e & 63;
      gload_lds16(Ab + (long)row * 1024 + k0 + col, &At[e]);
    }
#pragma unroll
    for (int p = 0; p < PB; ++p) {
      int e = (p * 256 + t) * 8;
      int row = e >> 6, col = e & 63;
      gload_lds16(Bb + (long)row * 1024 + k0 + col, &Bt[e]);
    }
    __syncthreads();
#pragma unroll
    for (int kk = 0; kk < BK; kk += 32) {
      s16x8 af[FM], bf[FN];
#pragma unroll
      for (int m = 0; m < FM; ++m)
        af[m] = *(const s16x8*)&At[(wr + m * 16 + c) * BK + kk + g * 8];
#pragma unroll
      for (int n = 0; n < FN; ++n)
        bf[n] = *(const s16x8*)&Bt[(wc + n * 16 + c) * BK + kk + g * 8];
#pragma unroll
      for (int m = 0; m < FM; ++m)
#pragma unroll
        for (int n = 0; n < FN; ++n)
          acc[m][n] = __builtin_amdgcn_mfma_f32_16x16x32_bf16(af[m], bf[n], acc[m][n], 0, 0, 0);
    }
    __syncthreads();
  }

#pragma unroll
  for (int m = 0; m < FM; ++m)
#pragma unroll
    for (int n = 0; n < FN; ++n) {
      if constexpr (CMODE == 3) {
        int row0 = m0 + wr + m * 16 + g * 4;
        int col  = n0 + wc + n * 16 + c;
        unsigned p01 = cvt2fp8(acc[m][n][0] * 0.00390625f, acc[m][n][1] * 0.00390625f);
        unsigned p23 = cvt2fp8(acc[m][n][2] * 0.00390625f, acc[m][n][3] * 0.00390625f);
        unsigned char* Cp = (unsigned char*)Cout + cbase + (long)row0 * ldc + col;
        Cp[0]            = (unsigned char)p01;
        Cp[(long)ldc]    = (unsigned char)(p01 >> 8);
        Cp[(long)ldc*2]  = (unsigned char)p23;
        Cp[(long)ldc*3]  = (unsigned char)(p23 >> 8);
      } else {
#pragma unroll
        for (int r = 0; r < 4; ++r) {
          int row = wr + m * 16 + g * 4 + r;          // local row in tile
          int col = n0 + wc + n * 16 + c;             // global col
          int grow = m0 + row;
          float v = acc[m][n][r];
          if constexpr (CMODE == 0) {
            ((unsigned short*)Cout)[cbase + (long)grow * ldc + col] = f2bf(v);
          } else if constexpr (CMODE == 1) {
            ((unsigned short*)Cout)[cbase + (long)col * ldc + grow] = f2bf(v);
          } else if constexpr (CMODE == 2) {
            ((float*)Cout)[cbase + (long)grow * ldc + col] = (col > grow) ? -1e9f : v;
          }
        }
      }
    }
}

// ---------------- flash attention (fp8 S-phase, 8 waves / 512 thr) ---------
// "Q" = Tf8[b,h] = (X M)/256 in e4m3 (128 q-rows per wg), keys = Xf8[b] e4m3,
// V via VT[b,h][64][1024] bf16.  Out: concat[b][n][h*64+v] bf16.
// LDS (48 KB): Tt[128][128]fp8 | Xt[128][128]fp8 | Vt[64][128]bf16;
// Pl[128][128]bf16 aliases Tt+Xt.
// Round-11 change: 256->512 threads (8 waves, 16 q-rows/wave), SAME tile and
// staging volume -> per-block efficiency kept, waves/SIMD 2->4 (TLP 2x).
// [r6's QBLK=64 failed because it halved tile efficiency; this doesn't.]
// fp8 swizzle: 16B units, unit' = unit^(row&7) on 128B rows; staged tiles
// keep LDS linear + inverse-swizzle the GLOBAL source (rule #21).
// Softmax scale = 8 (1/32 score * 256 T-prescale).
// Lessons: 128-VGPR budget via bounds(512,4) [r2: don't exceed]; single-buffer
// k0 [r5 dbuf null]; QBLK=128 [r6]; one accS set [r4].
__global__ __launch_bounds__(512, 4)
void flash_attn(const unsigned char* __restrict__ T, const unsigned char* __restrict__ X,
                const unsigned short* __restrict__ VT, unsigned short* __restrict__ Yc)
{
  __shared__ __align__(16) unsigned char Sh[49152]; // 48 KB
  unsigned char* Tt = Sh;                             // [128][128] fp8
  unsigned char* Xt = Sh + 16384;                     // [128][128] fp8
  unsigned short* Vt = (unsigned short*)(Sh + 32768); // [64][128] bf16
  unsigned short* Pl = (unsigned short*)Sh;           // [128][128] bf16, aliases Tt/Xt

  // T1 XCD swizzle
  unsigned fid = blockIdx.x + gridDim.x * blockIdx.y;
  unsigned nwg = gridDim.x * gridDim.y;
  unsigned sid = xcd_swz(fid, nwg);
  const int q0 = (sid % gridDim.x) * 128;
  const int bh = sid / gridDim.x;

  const int t = threadIdx.x;
  const int l = t & 63;
  const int w = t >> 6;          // 0..7
  const int g = l >> 4;
  const int c = l & 15;
  const int b = bh >> 4;

  const unsigned char* Tq = T + (long)bh * (1024 * 1024) + (long)q0 * 1024;
  const unsigned char* Xb = X + (long)b * (1024 * 1024);
  const unsigned short* Vb = VT + (long)bh * (64 * 1024);

  f32x4 accO[4] = {};
  float mrun[4], lrun[4];
#pragma unroll
  for (int r = 0; r < 4; ++r) { mrun[r] = -1e30f; lrun[r] = 0.f; }

  const float scale = 8.0f; // (1/32 score scale) * 256 (T prescale)

  for (int m0 = 0; m0 < 1024; m0 += 128) {
    // ---- S = Tq(128xK) * Xkeys(128xK)^T, K=1024 tiled by 128 (fp8)
    f32x4 accS[8] = {};
    for (int k0 = 0; k0 < 1024; k0 += 128) {
#pragma unroll
      for (int p = 0; p < 2; ++p) {
        int e = (p * 512 + t) * 16;                 // byte offset in 16K tile
        int r = e >> 7, u = (e >> 4) & 7;
        int gcol = ((u ^ (r & 7)) << 4);            // inverse-swizzled src col
        gload_lds16(Tq + (long)r * 1024 + k0 + gcol, &Tt[e]);
      }
#pragma unroll
      for (int p = 0; p < 2; ++p) {
        int e = (p * 512 + t) * 16;
        int r = e >> 7, u = (e >> 4) & 7;
        int gcol = ((u ^ (r & 7)) << 4);
        gload_lds16(Xb + (long)(m0 + r) * 1024 + k0 + gcol, &Xt[e]);
      }
      __syncthreads();
#pragma unroll
      for (int kk = 0; kk < 128; kk += 32) {
        long af, bf[8];
        {
          int row = w * 16 + c;
          int un = (kk >> 4) + (g >> 1);
          af = *(const long*)&Tt[row * 128 + ((un ^ (row & 7)) << 4) + (g & 1) * 8];
        }
#pragma unroll
        for (int n = 0; n < 8; ++n) {
          int row = n * 16 + c;
          int un = (kk >> 4) + (g >> 1);
          bf[n] = *(const long*)&Xt[row * 128 + ((un ^ (row & 7)) << 4) + (g & 1) * 8];
        }
        __builtin_amdgcn_s_setprio(1);
#pragma unroll
        for (int n = 0; n < 8; ++n)
          accS[n] = __builtin_amdgcn_mfma_f32_16x16x32_fp8_fp8(af, bf[n], accS[n], 0, 0, 0);
        __builtin_amdgcn_s_setprio(0);
      }
      __syncthreads();
    }
    // stage VT slab [64][128] bf16 for this keyblock (flies under softmax)
#pragma unroll
    for (int p = 0; p < 2; ++p) {
      int e = (p * 512 + t) * 8;                    // element (short) offset
      int r = e >> 7, u = (e >> 3) & 15;
      int gcol = ((u ^ (r & 7)) << 3);
      gload_lds16(Vb + (long)r * 1024 + m0 + gcol, &Vt[e]);
    }
    // ---- online softmax update (rows spread over 16-lane groups)
    float alpha[4];
#pragma unroll
    for (int r = 0; r < 4; ++r) {
      float mx = -1e30f;
#pragma unroll
      for (int n = 0; n < 8; ++n) mx = fmaxf(mx, accS[n][r]);
#pragma unroll
      for (int s = 1; s < 16; s <<= 1) mx = fmaxf(mx, __shfl_xor(mx, s));
      mx *= scale;
      float mnew = fmaxf(mrun[r], mx);
      float a = __expf(mrun[r] - mnew);
      alpha[r] = a;
      float sum = 0.f;
#pragma unroll
      for (int n = 0; n < 8; ++n) {
        float pe = __expf(accS[n][r] * scale - mnew);
        accS[n][r] = pe;
        sum += pe;
      }
#pragma unroll
      for (int s = 1; s < 16; s <<= 1) sum += __shfl_xor(sum, s);
      lrun[r] = lrun[r] * a + sum;
      mrun[r] = mnew;
    }
    // P -> LDS (bf16, swizzled), aliases Tt/Xt (safe: last k0 barrier passed)
#pragma unroll
    for (int n = 0; n < 8; ++n)
#pragma unroll
      for (int r = 0; r < 4; ++r) {
        int row = w * 16 + g * 4 + r;
        int un = 2 * n + (c >> 3);
        Pl[row * 128 + ((un ^ (row & 7)) << 3) + (c & 7)] = f2bf(accS[n][r]);
      }
    __syncthreads();   // Pl visible + Vt staged (vmcnt drained by barrier)
    // ---- O = O*alpha + P(16x128) @ V(128x64)   (bf16)
#pragma unroll
    for (int n = 0; n < 4; ++n)
#pragma unroll
      for (int r = 0; r < 4; ++r)
        accO[n][r] *= alpha[r];
#pragma unroll
    for (int kk = 0; kk < 128; kk += 32) {
      s16x8 pa, vb[4];
      {
        int row = w * 16 + c;
        int un = (kk >> 3) + g;
        pa = *(const s16x8*)&Pl[row * 128 + ((un ^ (row & 7)) << 3)];
      }
#pragma unroll
      for (int n = 0; n < 4; ++n) {
        int row = n * 16 + c;
        int un = (kk >> 3) + g;
        vb[n] = *(const s16x8*)&Vt[row * 128 + ((un ^ (row & 7)) << 3)];
      }
      __builtin_amdgcn_s_setprio(1);
#pragma unroll
      for (int n = 0; n < 4; ++n)
        accO[n] = __builtin_amdgcn_mfma_f32_16x16x32_bf16(pa, vb[n], accO[n], 0, 0, 0);
      __builtin_amdgcn_s_setprio(0);
    }
    __syncthreads();   // all done reading Pl/Vt before next m0 restage
  }
  // epilogue: divide by row-sum, write concat
  unsigned short* out = Yc + (long)b * (1024 * 1024) + (long)(bh & 15) * 64;
#pragma unroll
  for (int n = 0; n < 4; ++n)
#pragma unroll
    for (int r = 0; r < 4; ++r) {
      int row = q0 + w * 16 + g * 4 + r;
      int col = n * 16 + c;
      out[(long)row * 1024 + col] = f2bf(accO[n][r] / lrun[r]);
    }
}

// ---------------- launch ----------------
extern "C" void kernel_launch(void* const* d_in, const int* in_sizes, int n_in,
                              void* d_out, int out_size, void* d_ws, size_t ws_size,
                              hipStream_t stream) {
  (void)in_sizes; (void)n_in; (void)out_size; (void)ws_size;
  const float* X  = (const float*)d_in[0];
  const float* Wq = (const float*)d_in[1];
  const float* Wk = (const float*)d_in[2];
  const float* Wv = (const float*)d_in[3];
  const float* Wo = (const float*)d_in[4];
  float* Y = (float*)d_out;
  char* ws = (char*)d_ws;

  const long MB = 1L << 20;
  unsigned short* Xbf  = (unsigned short*)(ws + 0);          // 8 MB
  unsigned short* Wqb  = (unsigned short*)(ws + 8  * MB);    // 32 MB
  unsigned short* Wkb  = (unsigned short*)(ws + 40 * MB);    // 32 MB
  unsigned short* Mt   = (unsigned short*)(ws + 72 * MB);    // 32 MB
  unsigned char*  Tf8  = (unsigned char*)(ws + 104 * MB);    // 64 MB (fp8)
  unsigned char*  Xf8  = (unsigned char*)(ws + 168 * MB);    // 4 MB (fp8) -> 172 MB peak
  unsigned short* WvT  = (unsigned short*)(ws + 8  * MB);    // reuse (Wq dead after Mt)
  unsigned short* VTb  = (unsigned short*)(ws + 10 * MB);    // 8 MB
  unsigned short* Ccat = (unsigned short*)(ws + 18 * MB);    // 8 MB
  unsigned short* WoT  = (unsigned short*)(ws + 26 * MB);    // 2 MB

  const long M1 = 1L << 20; // element stride for [1024][1024]

  // converts (X: bf16 + fp8 in one pass)
  conv_x   <<<2048, 256, 0, stream>>>(X,  Xbf, Xf8, 524288);
  conv_bf16<<<8192, 256, 0, stream>>>(Wq, Wqb, 2097152);
  conv_bf16<<<8192, 256, 0, stream>>>(Wk, Wkb, 2097152);

  // Mt[h] = Wk[h] @ Wq[h]^T   (= M^T), bf16
  gemm_bt<128, 128, 2, 2, 0><<<dim3(8, 8, 16), 256, 0, stream>>>(
      Wkb, Wqb, Mt, 1, M1, 16, M1, M1, 1024);

  // T[b,h] = X[b] @ M[h], output scaled 1/256 -> fp8 e4m3 (HW cvt epilogue)
  gemm_bt<128, 128, 2, 2, 3><<<dim3(8, 8, 64), 256, 0, stream>>>(
      Xbf, Mt, Tf8, 16, M1, 16, M1, M1, 1024);

  // V^T[b,h][64][1024] = (X[b] @ Wv[h]) transposed-store, bf16
  convT_wv<<<4096, 256, 0, stream>>>(Wv, WvT);
  gemm_bt<128, 64, 4, 1, 1><<<dim3(1, 8, 64), 256, 0, stream>>>(
      Xbf, WvT, VTb, 16, M1, 16, 65536, 65536, 1024);

  // flash attention (fp8 S-phase, 8 waves) -> concat [B][N][H*64] bf16
  flash_attn<<<dim3(8, 64), 512, 0, stream>>>(Tf8, Xf8, VTb, Ccat);

  // Y = concat @ Wo, masked epilogue (col > row -> -1e9), fp32 out;
  // fully-masked tiles (n0 > m0+127) skip their K-loop.
  convT_wo<<<4096, 256, 0, stream>>>(Wo, WoT);
  gemm_bt<128, 128, 2, 2, 2><<<dim3(8, 8, 4), 256, 0, stream>>>(
      Ccat, WoT, Y, 1, M1, 1, 0, M1, 1024);
}

// Round 12
// 389.513 us; speedup vs baseline: 1.3540x; 1.3540x over previous
//
#include <hip/hip_runtime.h>
#include <stdint.h>

typedef short s16x8 __attribute__((ext_vector_type(8)));
typedef float f32x4 __attribute__((ext_vector_type(4)));

__device__ __forceinline__ unsigned short f2bf(float f) {
  union { float f; unsigned int u; } v; v.f = f;
  unsigned int r = v.u + 0x7FFFu + ((v.u >> 16) & 1u);
  return (unsigned short)(r >> 16);
}

// HW packed f32x2 -> e4m3x2 (low word: byte0=cvt(a), byte1=cvt(b))
__device__ __forceinline__ unsigned cvt2fp8(float a, float b) {
#if __has_builtin(__builtin_amdgcn_cvt_pk_fp8_f32)
  return (unsigned)__builtin_amdgcn_cvt_pk_fp8_f32(a, b, 0, false);
#else
  unsigned r;
  asm("v_cvt_pk_fp8_f32 %0, %1, %2" : "=v"(r) : "v"(a), "v"(b));
  return r;
#endif
}

__device__ __forceinline__ void gload_lds16(const void* g, void* l) {
  __builtin_amdgcn_global_load_lds(
      (const __attribute__((address_space(1))) unsigned int*)g,
      (__attribute__((address_space(3))) unsigned int*)l, 16, 0, 0);
}

// T1 XCD-aware bijective block swizzle (grid size must be %8==0; all ours are).
__device__ __forceinline__ unsigned xcd_swz(unsigned fid, unsigned nwg) {
  unsigned cpx = nwg >> 3;
  return (fid & 7) * cpx + (fid >> 3);
}

// ---------------- converts ----------------
__global__ void conv_bf16(const float* __restrict__ in, unsigned short* __restrict__ out, int n8) {
  int i = blockIdx.x * blockDim.x + threadIdx.x;
  if (i >= n8) return;
  const f32x4* p = (const f32x4*)(in + (long)i * 8);
  f32x4 a = p[0], b = p[1];
  s16x8 o;
  o[0]=(short)f2bf(a[0]); o[1]=(short)f2bf(a[1]); o[2]=(short)f2bf(a[2]); o[3]=(short)f2bf(a[3]);
  o[4]=(short)f2bf(b[0]); o[5]=(short)f2bf(b[1]); o[6]=(short)f2bf(b[2]); o[7]=(short)f2bf(b[3]);
  *(s16x8*)(out + (long)i * 8) = o;
}

// X f32 -> bf16 AND fp8 e4m3 in one pass (read X once)
__global__ void conv_x(const float* __restrict__ in, unsigned short* __restrict__ obf,
                       unsigned char* __restrict__ of8, int n8) {
  int i = blockIdx.x * blockDim.x + threadIdx.x;
  if (i >= n8) return;
  const f32x4* p = (const f32x4*)(in + (long)i * 8);
  f32x4 a = p[0], b = p[1];
  s16x8 o;
  o[0]=(short)f2bf(a[0]); o[1]=(short)f2bf(a[1]); o[2]=(short)f2bf(a[2]); o[3]=(short)f2bf(a[3]);
  o[4]=(short)f2bf(b[0]); o[5]=(short)f2bf(b[1]); o[6]=(short)f2bf(b[2]); o[7]=(short)f2bf(b[3]);
  *(s16x8*)(obf + (long)i * 8) = o;
  unsigned long w = (unsigned long)(cvt2fp8(a[0], a[1]) & 0xFFFFu)
                  | ((unsigned long)(cvt2fp8(a[2], a[3]) & 0xFFFFu) << 16)
                  | ((unsigned long)(cvt2fp8(b[0], b[1]) & 0xFFFFu) << 32)
                  | ((unsigned long)(cvt2fp8(b[2], b[3]) & 0xFFFFu) << 48);
  *(unsigned long*)(of8 + (long)i * 8) = w;
}

// Wv: [16][1024][64] f32 -> WvT [16][64][1024] bf16
__global__ void convT_wv(const float* __restrict__ in, unsigned short* __restrict__ out) {
  int i = blockIdx.x * blockDim.x + threadIdx.x; // 1M
  int v = i & 63, d = (i >> 6) & 1023, h = i >> 16;
  out[((long)h * 64 + v) * 1024 + d] = f2bf(in[i]);
}

// Wo: [1024][1024] f32 [c][e] -> WoT [e][c] bf16
__global__ void convT_wo(const float* __restrict__ in, unsigned short* __restrict__ out) {
  int i = blockIdx.x * blockDim.x + threadIdx.x; // 1M
  int e = i & 1023, c = i >> 10;
  out[(long)e * 1024 + c] = f2bf(in[i]);
}

// ---------------- generic bt-GEMM (bf16 in), K=1024 fixed ----------------
// C[i][j] = sum_k A[i][k] * BT[j][k];  A,BT bf16 row-major with ld=1024.
// CMODE 0: bf16 C[row*ldc+col]; 1: bf16 transposed C[col*ldc+row];
// 2: f32 masked (col>row -> -1e9); 3: fp8 e4m3 of (v/256) via HW cvt (cbase/ldc in BYTES).
template<int BM, int BN, int WAVES_M, int WAVES_N, int CMODE>
__global__ __launch_bounds__(256, 2)
void gemm_bt(const unsigned short* __restrict__ A, const unsigned short* __restrict__ BT,
             void* __restrict__ Cout, int aDiv, long aStr, int bMod, long bStr,
             long cStr, int ldc)
{
  constexpr int BK = 64;
  constexpr int FM = BM / (WAVES_M * 16);
  constexpr int FN = BN / (WAVES_N * 16);
  __shared__ __align__(16) unsigned short At[BM * BK];
  __shared__ __align__(16) unsigned short Bt[BN * BK];

  // T1 XCD swizzle
  unsigned fid = blockIdx.x + gridDim.x * (blockIdx.y + gridDim.y * blockIdx.z);
  unsigned nwg = gridDim.x * gridDim.y * gridDim.z;
  unsigned sid = xcd_swz(fid, nwg);
  unsigned bx = sid % gridDim.x;
  unsigned rem = sid / gridDim.x;
  unsigned by = rem % gridDim.y;
  unsigned bz = rem / gridDim.y;

  const int t = threadIdx.x;
  const int l = t & 63;
  const int g = l >> 4, c = l & 15;
  const int w = t >> 6;
  const int wr = (w / WAVES_N) * (BM / WAVES_M);
  const int wc = (w % WAVES_N) * (BN / WAVES_N);
  const int z = bz;
  const int m0 = by * BM;
  const int n0 = bx * BN;
  const unsigned short* Ab = A + (long)(z / aDiv) * aStr + (long)m0 * 1024;
  const unsigned short* Bb = BT + (long)(z % bMod) * bStr + (long)n0 * 1024;

  const long cbase = (long)z * cStr;

  // fully-masked output tile (col > row everywhere): skip the GEMM entirely
  if constexpr (CMODE == 2) {
    if (n0 > m0 + BM - 1) {
#pragma unroll
      for (int m = 0; m < FM; ++m)
#pragma unroll
        for (int n = 0; n < FN; ++n)
#pragma unroll
          for (int r = 0; r < 4; ++r) {
            int row = wr + m * 16 + g * 4 + r;
            int col = n0 + wc + n * 16 + c;
            ((float*)Cout)[cbase + (long)(m0 + row) * ldc + col] = -1e9f;
          }
      return;
    }
  }

  f32x4 acc[FM][FN] = {};
  constexpr int PA = (BM * BK) / 2048;
  constexpr int PB = (BN * BK) / 2048;

  for (int k0 = 0; k0 < 1024; k0 += BK) {
#pragma unroll
    for (int p = 0; p < PA; ++p) {
      int e = (p * 256 + t) * 8;
      int row = e >> 6, col = e & 63;
      gload_lds16(Ab + (long)row * 1024 + k0 + col, &At[e]);
    }
#pragma unroll
    for (int p = 0; p < PB; ++p) {
      int e = (p * 256 + t) * 8;
      int row = e >> 6, col = e & 63;
      gload_lds16(Bb + (long)row * 1024 + k0 + col, &Bt[e]);
    }
    __syncthreads();
#pragma unroll
    for (int kk = 0; kk < BK; kk += 32) {
      s16x8 af[FM], bf[FN];
#pragma unroll
      for (int m = 0; m < FM; ++m)
        af[m] = *(const s16x8*)&At[(wr + m * 16 + c) * BK + kk + g * 8];
#pragma unroll
      for (int n = 0; n < FN; ++n)
        bf[n] = *(const s16x8*)&Bt[(wc + n * 16 + c) * BK + kk + g * 8];
#pragma unroll
      for (int m = 0; m < FM; ++m)
#pragma unroll
        for (int n = 0; n < FN; ++n)
          acc[m][n] = __builtin_amdgcn_mfma_f32_16x16x32_bf16(af[m], bf[n], acc[m][n], 0, 0, 0);
    }
    __syncthreads();
  }

#pragma unroll
  for (int m = 0; m < FM; ++m)
#pragma unroll
    for (int n = 0; n < FN; ++n) {
      if constexpr (CMODE == 3) {
        int row0 = m0 + wr + m * 16 + g * 4;
        int col  = n0 + wc + n * 16 + c;
        unsigned p01 = cvt2fp8(acc[m][n][0] * 0.00390625f, acc[m][n][1] * 0.00390625f);
        unsigned p23 = cvt2fp8(acc[m][n][2] * 0.00390625f, acc[m][n][3] * 0.00390625f);
        unsigned char* Cp = (unsigned char*)Cout + cbase + (long)row0 * ldc + col;
        Cp[0]            = (unsigned char)p01;
        Cp[(long)ldc]    = (unsigned char)(p01 >> 8);
        Cp[(long)ldc*2]  = (unsigned char)p23;
        Cp[(long)ldc*3]  = (unsigned char)(p23 >> 8);
      } else {
#pragma unroll
        for (int r = 0; r < 4; ++r) {
          int row = wr + m * 16 + g * 4 + r;          // local row in tile
          int col = n0 + wc + n * 16 + c;             // global col
          int grow = m0 + row;
          float v = acc[m][n][r];
          if constexpr (CMODE == 0) {
            ((unsigned short*)Cout)[cbase + (long)grow * ldc + col] = f2bf(v);
          } else if constexpr (CMODE == 1) {
            ((unsigned short*)Cout)[cbase + (long)col * ldc + grow] = f2bf(v);
          } else if constexpr (CMODE == 2) {
            ((float*)Cout)[cbase + (long)grow * ldc + col] = (col > grow) ? -1e9f : v;
          }
        }
      }
    }
}

// ---------------- fp8 bt-GEMM for T = X @ M (BK=128, fp8 in/out) ----------
// A = Xf8 [b][1024][1024B], BT = Mtf8 [h][1024][1024B] (= M^T/256 e4m3).
// acc = sum x * (m/256) = T/256; epilogue stores cvt(acc) directly -> Tf8.
// Same 2-barrier structure as gemm_bt; BK=128 fp8 keeps LDS at 32 KB (same
// occupancy as bf16 BK=64) while HALVING barrier count (16->8) and staged
// bytes (512->256 KB/block).  128B rows + 16B-unit XOR swizzle unit^(row&7);
// fragment addressing identical to the validated r10 flash S-phase.
__global__ __launch_bounds__(256, 2)
void gemm_f8(const unsigned char* __restrict__ A, const unsigned char* __restrict__ BT,
             unsigned char* __restrict__ Cout)
{
  __shared__ __align__(16) unsigned char At[128 * 128];
  __shared__ __align__(16) unsigned char Bt[128 * 128];

  // T1 XCD swizzle
  unsigned fid = blockIdx.x + gridDim.x * (blockIdx.y + gridDim.y * blockIdx.z);
  unsigned nwg = gridDim.x * gridDim.y * gridDim.z;
  unsigned sid = xcd_swz(fid, nwg);
  unsigned bx = sid % gridDim.x;
  unsigned rem = sid / gridDim.x;
  unsigned by = rem % gridDim.y;
  unsigned bz = rem / gridDim.y;

  const int t = threadIdx.x;
  const int l = t & 63;
  const int g = l >> 4, c = l & 15;
  const int w = t >> 6;                 // 4 waves, 2x2
  const int wr = (w >> 1) * 64;
  const int wc = (w & 1) * 64;
  const int z = bz;                     // 0..63: b = z/16, h = z%16
  const int m0 = by * 128;
  const int n0 = bx * 128;
  const unsigned char* Ab = A + (long)(z >> 4) * (1 << 20) + (long)m0 * 1024;
  const unsigned char* Bb = BT + (long)(z & 15) * (1 << 20) + (long)n0 * 1024;

  f32x4 acc[4][4] = {};

  for (int k0 = 0; k0 < 1024; k0 += 128) {
#pragma unroll
    for (int p = 0; p < 4; ++p) {
      int e = (p * 256 + t) * 16;       // byte offset in 16K tile
      int r = e >> 7, u = (e >> 4) & 7;
      int gcol = ((u ^ (r & 7)) << 4);  // inverse-swizzled source col (bytes)
      gload_lds16(Ab + (long)r * 1024 + k0 + gcol, &At[e]);
    }
#pragma unroll
    for (int p = 0; p < 4; ++p) {
      int e = (p * 256 + t) * 16;
      int r = e >> 7, u = (e >> 4) & 7;
      int gcol = ((u ^ (r & 7)) << 4);
      gload_lds16(Bb + (long)r * 1024 + k0 + gcol, &Bt[e]);
    }
    __syncthreads();
#pragma unroll
    for (int kk = 0; kk < 128; kk += 32) {
      long af[4], bf[4];
#pragma unroll
      for (int m = 0; m < 4; ++m) {
        int row = wr + m * 16 + c;
        int un = (kk >> 4) + (g >> 1);
        af[m] = *(const long*)&At[row * 128 + ((un ^ (row & 7)) << 4) + (g & 1) * 8];
      }
#pragma unroll
      for (int n = 0; n < 4; ++n) {
        int row = wc + n * 16 + c;
        int un = (kk >> 4) + (g >> 1);
        bf[n] = *(const long*)&Bt[row * 128 + ((un ^ (row & 7)) << 4) + (g & 1) * 8];
      }
      __builtin_amdgcn_s_setprio(1);
#pragma unroll
      for (int m = 0; m < 4; ++m)
#pragma unroll
        for (int n = 0; n < 4; ++n)
          acc[m][n] = __builtin_amdgcn_mfma_f32_16x16x32_fp8_fp8(af[m], bf[n], acc[m][n], 0, 0, 0);
      __builtin_amdgcn_s_setprio(0);
    }
    __syncthreads();
  }

  const long cbase = (long)z << 20;     // bytes
#pragma unroll
  for (int m = 0; m < 4; ++m)
#pragma unroll
    for (int n = 0; n < 4; ++n) {
      int row0 = m0 + wr + m * 16 + g * 4;
      int col  = n0 + wc + n * 16 + c;
      unsigned p01 = cvt2fp8(acc[m][n][0], acc[m][n][1]);
      unsigned p23 = cvt2fp8(acc[m][n][2], acc[m][n][3]);
      unsigned char* Cp = Cout + cbase + (long)row0 * 1024 + col;
      Cp[0]    = (unsigned char)p01;
      Cp[1024] = (unsigned char)(p01 >> 8);
      Cp[2048] = (unsigned char)p23;
      Cp[3072] = (unsigned char)(p23 >> 8);
    }
}

// ---------------- flash attention (r10: fp8 S-phase, BK=128, 4 waves) ------
// "Q" = Tf8[b,h] = (X M)/256 in e4m3 (128 q-rows per wg), keys = Xf8[b] e4m3,
// V via VT[b,h][64][1024] bf16.  Out: concat[b][n][h*64+v] bf16.
// LDS (48 KB): Tt[128][128]fp8 | Xt[128][128]fp8 | Vt[64][128]bf16;
// Pl[128][128]bf16 aliases Tt+Xt.  128B fp8 rows, 16B-unit XOR unit^(row&7);
// staged tiles keep LDS linear + inverse-swizzle the GLOBAL source (rule #21).
// Softmax scale = 8 (1/32 score * 256 T-prescale).
// Lessons: bounds(256,2)+4 waves is the local optimum [r2 spills at 3; r5
// dbuf null; r6 QBLK=64 and r11 8-wave both diluted MFMA/LDS-read ratio].
__global__ __launch_bounds__(256, 2)
void flash_attn(const unsigned char* __restrict__ T, const unsigned char* __restrict__ X,
                const unsigned short* __restrict__ VT, unsigned short* __restrict__ Yc)
{
  __shared__ __align__(16) unsigned char Sh[49152]; // 48 KB
  unsigned char* Tt = Sh;                             // [128][128] fp8
  unsigned char* Xt = Sh + 16384;                     // [128][128] fp8
  unsigned short* Vt = (unsigned short*)(Sh + 32768); // [64][128] bf16
  unsigned short* Pl = (unsigned short*)Sh;           // [128][128] bf16, aliases Tt/Xt

  // T1 XCD swizzle
  unsigned fid = blockIdx.x + gridDim.x * blockIdx.y;
  unsigned nwg = gridDim.x * gridDim.y;
  unsigned sid = xcd_swz(fid, nwg);
  const int q0 = (sid % gridDim.x) * 128;
  const int bh = sid / gridDim.x;

  const int t = threadIdx.x;
  const int l = t & 63;
  const int w = t >> 6;
  const int g = l >> 4;
  const int c = l & 15;
  const int b = bh >> 4;

  const unsigned char* Tq = T + (long)bh * (1024 * 1024) + (long)q0 * 1024;
  const unsigned char* Xb = X + (long)b * (1024 * 1024);
  const unsigned short* Vb = VT + (long)bh * (64 * 1024);

  f32x4 accO[2][4] = {};
  float mrun[2][4], lrun[2][4];
#pragma unroll
  for (int m = 0; m < 2; ++m)
#pragma unroll
    for (int r = 0; r < 4; ++r) { mrun[m][r] = -1e30f; lrun[m][r] = 0.f; }

  const float scale = 8.0f; // (1/32 score scale) * 256 (T prescale)

  for (int m0 = 0; m0 < 1024; m0 += 128) {
    // ---- S = Tq(128xK) * Xkeys(128xK)^T, K=1024 tiled by 128 (fp8)
    f32x4 accS[2][8] = {};
    for (int k0 = 0; k0 < 1024; k0 += 128) {
#pragma unroll
      for (int p = 0; p < 4; ++p) {
        int e = (p * 256 + t) * 16;                 // byte offset in 16K tile
        int r = e >> 7, u = (e >> 4) & 7;
        int gcol = ((u ^ (r & 7)) << 4);            // inverse-swizzled src col
        gload_lds16(Tq + (long)r * 1024 + k0 + gcol, &Tt[e]);
      }
#pragma unroll
      for (int p = 0; p < 4; ++p) {
        int e = (p * 256 + t) * 16;
        int r = e >> 7, u = (e >> 4) & 7;
        int gcol = ((u ^ (r & 7)) << 4);
        gload_lds16(Xb + (long)(m0 + r) * 1024 + k0 + gcol, &Xt[e]);
      }
      __syncthreads();
#pragma unroll
      for (int kk = 0; kk < 128; kk += 32) {
        long af[2], bf[8];
#pragma unroll
        for (int m = 0; m < 2; ++m) {
          int row = w * 32 + m * 16 + c;
          int un = (kk >> 4) + (g >> 1);
          af[m] = *(const long*)&Tt[row * 128 + ((un ^ (row & 7)) << 4) + (g & 1) * 8];
        }
#pragma unroll
        for (int n = 0; n < 8; ++n) {
          int row = n * 16 + c;
          int un = (kk >> 4) + (g >> 1);
          bf[n] = *(const long*)&Xt[row * 128 + ((un ^ (row & 7)) << 4) + (g & 1) * 8];
        }
        __builtin_amdgcn_s_setprio(1);
#pragma unroll
        for (int m = 0; m < 2; ++m)
#pragma unroll
          for (int n = 0; n < 8; ++n)
            accS[m][n] = __builtin_amdgcn_mfma_f32_16x16x32_fp8_fp8(af[m], bf[n], accS[m][n], 0, 0, 0);
        __builtin_amdgcn_s_setprio(0);
      }
      __syncthreads();
    }
    // stage VT slab [64][128] bf16 for this keyblock (flies under softmax)
#pragma unroll
    for (int p = 0; p < 4; ++p) {
      int e = (p * 256 + t) * 8;                    // element (short) offset
      int r = e >> 7, u = (e >> 3) & 15;
      int gcol = ((u ^ (r & 7)) << 3);
      gload_lds16(Vb + (long)r * 1024 + m0 + gcol, &Vt[e]);
    }
    // ---- online softmax update (rows spread over 16-lane groups)
    float alpha[2][4];
#pragma unroll
    for (int m = 0; m < 2; ++m) {
#pragma unroll
      for (int r = 0; r < 4; ++r) {
        float mx = -1e30f;
#pragma unroll
        for (int n = 0; n < 8; ++n) mx = fmaxf(mx, accS[m][n][r]);
#pragma unroll
        for (int s = 1; s < 16; s <<= 1) mx = fmaxf(mx, __shfl_xor(mx, s));
        mx *= scale;
        float mnew = fmaxf(mrun[m][r], mx);
        float a = __expf(mrun[m][r] - mnew);
        alpha[m][r] = a;
        float sum = 0.f;
#pragma unroll
        for (int n = 0; n < 8; ++n) {
          float pe = __expf(accS[m][n][r] * scale - mnew);
          accS[m][n][r] = pe;
          sum += pe;
        }
#pragma unroll
        for (int s = 1; s < 16; s <<= 1) sum += __shfl_xor(sum, s);
        lrun[m][r] = lrun[m][r] * a + sum;
        mrun[m][r] = mnew;
      }
    }
    // P -> LDS (bf16, swizzled), aliases Tt/Xt (safe: last k0 barrier passed)
#pragma unroll
    for (int m = 0; m < 2; ++m)
#pragma unroll
      for (int n = 0; n < 8; ++n)
#pragma unroll
        for (int r = 0; r < 4; ++r) {
          int row = w * 32 + m * 16 + g * 4 + r;
          int un = 2 * n + (c >> 3);
          Pl[row * 128 + ((un ^ (row & 7)) << 3) + (c & 7)] = f2bf(accS[m][n][r]);
        }
    __syncthreads();   // Pl visible + Vt staged (vmcnt drained by barrier)
    // ---- O = O*alpha + P(32x128) @ V(128x64)   (bf16)
#pragma unroll
    for (int m = 0; m < 2; ++m)
#pragma unroll
      for (int n = 0; n < 4; ++n)
#pragma unroll
        for (int r = 0; r < 4; ++r)
          accO[m][n][r] *= alpha[m][r];
#pragma unroll
    for (int kk = 0; kk < 128; kk += 32) {
      s16x8 pa[2], vb[4];
#pragma unroll
      for (int m = 0; m < 2; ++m) {
        int row = w * 32 + m * 16 + c;
        int un = (kk >> 3) + g;
        pa[m] = *(const s16x8*)&Pl[row * 128 + ((un ^ (row & 7)) << 3)];
      }
#pragma unroll
      for (int n = 0; n < 4; ++n) {
        int row = n * 16 + c;
        int un = (kk >> 3) + g;
        vb[n] = *(const s16x8*)&Vt[row * 128 + ((un ^ (row & 7)) << 3)];
      }
      __builtin_amdgcn_s_setprio(1);
#pragma unroll
      for (int m = 0; m < 2; ++m)
#pragma unroll
        for (int n = 0; n < 4; ++n)
          accO[m][n] = __builtin_amdgcn_mfma_f32_16x16x32_bf16(pa[m], vb[n], accO[m][n], 0, 0, 0);
      __builtin_amdgcn_s_setprio(0);
    }
    __syncthreads();   // all done reading Pl/Vt before next m0 restage
  }
  // epilogue: divide by row-sum, write concat
  unsigned short* out = Yc + (long)b * (1024 * 1024) + (long)(bh & 15) * 64;
#pragma unroll
  for (int m = 0; m < 2; ++m)
#pragma unroll
    for (int n = 0; n < 4; ++n)
#pragma unroll
      for (int r = 0; r < 4; ++r) {
        int row = q0 + w * 32 + m * 16 + g * 4 + r;
        int col = n * 16 + c;
        out[(long)row * 1024 + col] = f2bf(accO[m][n][r] / lrun[m][r]);
      }
}

// ---------------- launch ----------------
extern "C" void kernel_launch(void* const* d_in, const int* in_sizes, int n_in,
                              void* d_out, int out_size, void* d_ws, size_t ws_size,
                              hipStream_t stream) {
  (void)in_sizes; (void)n_in; (void)out_size; (void)ws_size;
  const float* X  = (const float*)d_in[0];
  const float* Wq = (const float*)d_in[1];
  const float* Wk = (const float*)d_in[2];
  const float* Wv = (const float*)d_in[3];
  const float* Wo = (const float*)d_in[4];
  float* Y = (float*)d_out;
  char* ws = (char*)d_ws;

  const long MB = 1L << 20;
  unsigned short* Xbf  = (unsigned short*)(ws + 0);          // 8 MB
  unsigned short* Wqb  = (unsigned short*)(ws + 8  * MB);    // 32 MB
  unsigned short* Wkb  = (unsigned short*)(ws + 40 * MB);    // 32 MB
  unsigned char*  Mtf8 = (unsigned char*)(ws + 72 * MB);     // 16 MB (fp8)
  unsigned char*  Tf8  = (unsigned char*)(ws + 104 * MB);    // 64 MB (fp8)
  unsigned char*  Xf8  = (unsigned char*)(ws + 168 * MB);    // 4 MB  -> 172 MB peak
  unsigned short* WvT  = (unsigned short*)(ws + 8  * MB);    // reuse (Wq dead after Mt)
  unsigned short* VTb  = (unsigned short*)(ws + 10 * MB);    // 8 MB
  unsigned short* Ccat = (unsigned short*)(ws + 18 * MB);    // 8 MB
  unsigned short* WoT  = (unsigned short*)(ws + 26 * MB);    // 2 MB

  const long M1 = 1L << 20; // element/byte stride for [1024][1024]

  // converts (X: bf16 + fp8 in one pass)
  conv_x   <<<2048, 256, 0, stream>>>(X,  Xbf, Xf8, 524288);
  conv_bf16<<<8192, 256, 0, stream>>>(Wq, Wqb, 2097152);
  conv_bf16<<<8192, 256, 0, stream>>>(Wk, Wkb, 2097152);

  // Mtf8[h] = (Wk[h] @ Wq[h]^T)/256 in e4m3  (CMODE 3: cbase/ldc in bytes)
  gemm_bt<128, 128, 2, 2, 3><<<dim3(8, 8, 16), 256, 0, stream>>>(
      Wkb, Wqb, Mtf8, 1, M1, 16, M1, M1, 1024);

  // Tf8[b,h] = (X[b] @ M[h])/256 in e4m3  (fp8 GEMM, BK=128)
  gemm_f8<<<dim3(8, 8, 64), 256, 0, stream>>>(Xf8, Mtf8, Tf8);

  // V^T[b,h][64][1024] = (X[b] @ Wv[h]) transposed-store, bf16
  convT_wv<<<4096, 256, 0, stream>>>(Wv, WvT);
  gemm_bt<128, 64, 4, 1, 1><<<dim3(1, 8, 64), 256, 0, stream>>>(
      Xbf, WvT, VTb, 16, M1, 16, 65536, 65536, 1024);

  // flash attention (fp8 S-phase, BK=128) -> concat [B][N][H*64] bf16
  flash_attn<<<dim3(8, 64), 256, 0, stream>>>(Tf8, Xf8, VTb, Ccat);

  // Y = concat @ Wo, masked epilogue (col > row -> -1e9), fp32 out;
  // fully-masked tiles (n0 > m0+127) skip their K-loop.
  convT_wo<<<4096, 256, 0, stream>>>(Wo, WoT);
  gemm_bt<128, 128, 2, 2, 2><<<dim3(8, 8, 4), 256, 0, stream>>>(
      Ccat, WoT, Y, 1, M1, 1, 0, M1, 1024);
}